// Round 3
// baseline (562.413 us; speedup 1.0000x reference)
//
#include <hip/hip_runtime.h>
#include <stdint.h>

// Periodic radius-graph neighbor list (AlphaNet). B=16, N=256, C=27, M=6912.
// Outputs (flat f32 concat): dist [B,N,M], dvec [B,N,M,3], num_neighbors_image [B].
// keep = within-radius (1e-4 < dsqr <= 25) AND stable-sort rank < 32
//      == key (f32bits(dsqr)<<32 | m) among the 32 smallest within-radius keys.
//
// R3 structure (decouple stores from compute):
//   1) hipMemsetAsync zeros the whole 453 MB output (runtime fill path: 6.1 TB/s).
//   2) edges_kernel: per-receiver block computes the <=32 kept edges (bit-exact
//      numpy arithmetic) and appends them to a compact list in d_ws (~2 MB).
//   3) scatter_kernel: one thread per edge writes dist[id] and dvec[3*id..].

constexpr int B_ = 16, N_ = 256, C_ = 27;
constexpr int M_ = N_ * C_;        // 6912
constexpr int MAXC = 256;          // LDS candidate slots (mean ~78, 20-sigma margin)
constexpr int KMAX = 32;
constexpr int EMAX = B_ * N_ * KMAX;   // hard cap on kept edges: 131072

__global__ __launch_bounds__(256)
void edges_kernel(const float* __restrict__ pos,    // [B,N,3]
                  const float* __restrict__ cell,   // [B,3,3]
                  float* __restrict__ nn,           // [B] float counts (pre-zeroed)
                  int*   __restrict__ ectr,         // edge counter (pre-zeroed)
                  int*   __restrict__ eidx,         // [EMAX] flat id = bi*M + m
                  float4* __restrict__ evals)       // [EMAX] dx,dy,dz,dsq
{
#pragma clang fp contract(off)
    __shared__ float offx[C_], offy[C_], offz[C_];
    __shared__ unsigned long long keys[MAXC];
    __shared__ float4 vals[MAXC];
    __shared__ int cnt;

    const int bi  = blockIdx.x;   // b*N + i
    const int b   = bi >> 8;
    const int i   = bi & 255;
    const int tid = threadIdx.x;

    const float* pb = pos + b * N_ * 3;
    // thread owns source atom j = tid; receiver i is wave-uniform (scalar loads)
    const float pjx = pb[tid * 3 + 0], pjy = pb[tid * 3 + 1], pjz = pb[tid * 3 + 2];
    const float pix = pb[i * 3 + 0],   piy = pb[i * 3 + 1],   piz = pb[i * 3 + 2];

    if (tid < C_) {
        const float n1 = (float)(tid / 9 - 1);
        const float n2 = (float)((tid / 3) % 3 - 1);
        const float n3 = (float)(tid % 3 - 1);
        const float* cb = cell + b * 9;
        offx[tid] = n1 * cb[0] + n2 * cb[3] + n3 * cb[6];
        offy[tid] = n1 * cb[1] + n2 * cb[4] + n3 * cb[7];
        offz[tid] = n1 * cb[2] + n2 * cb[5] + n3 * cb[8];
    }
    if (tid == 0) cnt = 0;
    __syncthreads();

    // pass 1: bit-exact numpy order: s = pj + off; d = pi - s; ((dx*dx+dy*dy)+dz*dz)
    #pragma unroll 1
    for (int c = 0; c < C_; ++c) {
        const float sx = pjx + offx[c], sy = pjy + offy[c], sz = pjz + offz[c];
        const float dx = pix - sx, dy = piy - sy, dz = piz - sz;
        const float dsq = dx * dx + dy * dy + dz * dz;
        if (dsq <= 25.0f && dsq > 1e-4f) {
            const int idx = atomicAdd(&cnt, 1);
            if (idx < MAXC) {
                keys[idx] = ((unsigned long long)__float_as_uint(dsq) << 32)
                          | (unsigned)(tid * C_ + c);
                vals[idx] = make_float4(dx, dy, dz, dsq);
            }
        }
    }
    __syncthreads();

    int K = cnt; if (K > MAXC) K = MAXC;
    if (tid == 0)
        atomicAdd(&nn[b], (float)(K < KMAX ? K : KMAX));  // exact for small ints

    // rank scan (keys unique -> exactly min(K,32) writers); append to edge list
    for (int idx = tid; idx < K; idx += 256) {
        const unsigned long long key = keys[idx];
        int r = 0;
        for (int q = 0; q < K; ++q) r += (keys[q] < key) ? 1 : 0;
        if (r < KMAX) {
            const int e = atomicAdd(ectr, 1);   // wave-coalesced by compiler
            eidx[e]  = bi * M_ + (int)(key & 0xffffffffu);
            evals[e] = vals[idx];
        }
    }
}

__global__ __launch_bounds__(256)
void scatter_kernel(const int* __restrict__ ectr,
                    const int* __restrict__ eidx,
                    const float4* __restrict__ evals,
                    float* __restrict__ dist,      // [B*N*M]
                    float* __restrict__ dvec)      // [B*N*M*3]
{
    const int e = blockIdx.x * 256 + threadIdx.x;
    if (e >= *ectr) return;
    const int id = eidx[e];
    const float4 v = evals[e];
    dist[id] = sqrtf(v.w);
    dvec[3 * (size_t)id + 0] = v.x;
    dvec[3 * (size_t)id + 1] = v.y;
    dvec[3 * (size_t)id + 2] = v.z;
}

extern "C" void kernel_launch(void* const* d_in, const int* in_sizes, int n_in,
                              void* d_out, int out_size, void* d_ws, size_t ws_size,
                              hipStream_t stream)
{
    const float* pos  = (const float*)d_in[0];
    const float* cell = (const float*)d_in[1];
    float* dist = (float*)d_out;
    float* dvec = dist + (size_t)B_ * N_ * M_;
    float* nn   = dvec + (size_t)B_ * N_ * M_ * 3;

    // ws layout: [0..63] edge counter; [128 ..) eidx (EMAX ints); then evals (16B-aligned)
    int*    ectr  = (int*)d_ws;
    int*    eidx  = (int*)((char*)d_ws + 128);
    float4* evals = (float4*)((char*)d_ws + 128 + (size_t)EMAX * 4);  // offset 524416, 16B aligned

    // 1) zero the entire output (dist + dvec + nn): runtime fill path ~6.1 TB/s
    hipMemsetAsync(d_out, 0, (size_t)out_size * sizeof(float), stream);
    // 2) zero the edge counter
    hipMemsetAsync(d_ws, 0, 128, stream);
    // 3) compute kept edges into compact list
    edges_kernel<<<dim3(B_ * N_), dim3(256), 0, stream>>>(pos, cell, nn, ectr, eidx, evals);
    // 4) scatter edges into the zeroed output
    scatter_kernel<<<dim3(EMAX / 256), dim3(256), 0, stream>>>(ectr, eidx, evals, dist, dvec);
}

// Round 4
// 466.858 us; speedup vs baseline: 1.2047x; 1.2047x over previous
//
#include <hip/hip_runtime.h>
#include <stdint.h>

// Periodic radius-graph neighbor list (AlphaNet). B=16, N=256, C=27, M=6912.
// Outputs (flat f32 concat): dist [B,N,M], dvec [B,N,M,3], num_neighbors_image [B].
// keep = (1e-4 < dsqr <= 25) AND stable-sort rank < 32
//      == key (f32bits(dsqr)<<32 | m) among the 32 smallest within-radius keys.
//
// R4: fused per-receiver kernel, single store pass.
//  - pass 1: candidates -> LDS (bit-exact numpy arithmetic), LDS atomics only
//  - rank scan -> kept[32] (dx,dy,dz,dist) + direct-mapped slot[m] byte array
//  - merged fill: every float4 group stored exactly once; zero unless slot hit.
// No contended global atomics (R3's regression: 131K same-address atomicAdds).

constexpr int B_ = 16, N_ = 256, C_ = 27;
constexpr int M_ = N_ * C_;      // 6912
constexpr int MAXC = 256;        // candidate slots; mean ~78
constexpr int KMAX = 32;

__global__ __launch_bounds__(256)
void nbr_kernel(const float* __restrict__ pos,    // [B,N,3]
                const float* __restrict__ cell,   // [B,3,3]
                float* __restrict__ dist,         // [B,N,M]
                float* __restrict__ dvec,         // [B,N,M,3]
                float* __restrict__ nn)           // [B] (float counts, pre-zeroed)
{
#pragma clang fp contract(off)
    __shared__ float offx[C_], offy[C_], offz[C_];
    __shared__ unsigned long long keys[MAXC];
    __shared__ float4 vals[MAXC];               // dx,dy,dz,dsq
    __shared__ float4 kept[KMAX];               // dx,dy,dz,dist (by rank)
    __shared__ unsigned char slot[M_];          // 0 = empty, else rank+1
    __shared__ int cnt;

    const int bi  = blockIdx.x;   // b*N + i
    const int b   = bi >> 8;
    const int i   = bi & 255;
    const int tid = threadIdx.x;

    const float* pb = pos + b * N_ * 3;
    // thread owns source atom j = tid; receiver i is wave-uniform
    const float pjx = pb[tid * 3 + 0], pjy = pb[tid * 3 + 1], pjz = pb[tid * 3 + 2];
    const float pix = pb[i * 3 + 0],   piy = pb[i * 3 + 1],   piz = pb[i * 3 + 2];

    if (tid < C_) {
        const float n1 = (float)(tid / 9 - 1);
        const float n2 = (float)((tid / 3) % 3 - 1);
        const float n3 = (float)(tid % 3 - 1);
        const float* cb = cell + b * 9;
        offx[tid] = n1 * cb[0] + n2 * cb[3] + n3 * cb[6];
        offy[tid] = n1 * cb[1] + n2 * cb[4] + n3 * cb[7];
        offz[tid] = n1 * cb[2] + n2 * cb[5] + n3 * cb[8];
    }
    uint32_t* slot32 = (uint32_t*)slot;
    for (int w = tid; w < M_ / 4; w += 256) slot32[w] = 0;   // zero slot array
    if (tid == 0) cnt = 0;
    __syncthreads();

    // pass 1: bit-exact numpy order: s = pj + off; d = pi - s; ((dx*dx+dy*dy)+dz*dz)
    #pragma unroll 1
    for (int c = 0; c < C_; ++c) {
        const float sx = pjx + offx[c], sy = pjy + offy[c], sz = pjz + offz[c];
        const float dx = pix - sx, dy = piy - sy, dz = piz - sz;
        const float dsq = dx * dx + dy * dy + dz * dz;
        if (dsq <= 25.0f && dsq > 1e-4f) {
            const int idx = atomicAdd(&cnt, 1);              // LDS atomic
            if (idx < MAXC) {
                keys[idx] = ((unsigned long long)__float_as_uint(dsq) << 32)
                          | (unsigned)(tid * C_ + c);
                vals[idx] = make_float4(dx, dy, dz, dsq);
            }
        }
    }
    __syncthreads();

    int K = cnt; if (K > MAXC) K = MAXC;
    if (tid == 0)
        atomicAdd(&nn[b], (float)(K < KMAX ? K : KMAX));     // 16 addrs, light

    // rank scan (keys unique) -> kept table + slot map; rank gives compact index
    for (int idx = tid; idx < K; idx += 256) {
        const unsigned long long key = keys[idx];
        int r = 0;
        for (int q = 0; q < K; ++q) r += (keys[q] < key) ? 1 : 0;
        if (r < KMAX) {
            const int m = (int)(key & 0xffffffffu);
            const float4 v = vals[idx];
            kept[r] = make_float4(v.x, v.y, v.z, sqrtf(v.w));
            slot[m] = (unsigned char)(r + 1);
        }
    }
    __syncthreads();

    float4* dp = (float4*)(dist + (size_t)bi * M_);
    float4* vp = (float4*)(dvec + (size_t)bi * (size_t)(M_ * 3));

    // merged fill, dist region: 1728 groups, group g covers m = 4g..4g+3
    for (int g = tid; g < M_ / 4; g += 256) {
        float4 out = make_float4(0.f, 0.f, 0.f, 0.f);
        const uint32_t s4 = slot32[g];               // 4 slot bytes at once
        if (s4) {
            #pragma unroll
            for (int u = 0; u < 4; ++u) {
                const uint32_t s = (s4 >> (8 * u)) & 0xffu;
                if (s) (&out.x)[u] = kept[s - 1].w;
            }
        }
        dp[g] = out;
    }
    // merged fill, dvec region: 5184 groups; elements e=4h..4h+3, m=e/3, comp=e%3
    for (int h = tid; h < 3 * M_ / 4; h += 256) {
        const int e0 = 4 * h;
        const int m0 = e0 / 3;
        const int m1 = (e0 + 3) / 3;                 // at most 2 distinct m per group
        float4 out = make_float4(0.f, 0.f, 0.f, 0.f);
        if ((slot[m0] | slot[m1]) != 0) {
            #pragma unroll
            for (int u = 0; u < 4; ++u) {
                const int e = e0 + u;
                const int m = e / 3;
                const int d = e - 3 * m;
                const uint32_t s = slot[m];
                if (s) (&out.x)[u] = (&kept[s - 1].x)[d];
            }
        }
        vp[h] = out;
    }
}

extern "C" void kernel_launch(void* const* d_in, const int* in_sizes, int n_in,
                              void* d_out, int out_size, void* d_ws, size_t ws_size,
                              hipStream_t stream)
{
    const float* pos  = (const float*)d_in[0];
    const float* cell = (const float*)d_in[1];
    float* dist = (float*)d_out;
    float* dvec = dist + (size_t)B_ * N_ * M_;
    float* nn   = dvec + (size_t)B_ * N_ * M_ * 3;
    hipMemsetAsync(nn, 0, B_ * sizeof(float), stream);   // zero count tail only
    nbr_kernel<<<dim3(B_ * N_), dim3(256), 0, stream>>>(pos, cell, dist, dvec, nn);
}